// Round 1
// baseline (672.623 us; speedup 1.0000x reference)
//
#include <hip/hip_runtime.h>
#include <hip/hip_bf16.h>
#include <cstdint>

#define TOK 1024      // B*L
#define LSEQ 512
#define DMODEL 1024
#define DPROJ 6464
#define DPROJP 6528   // padded to 51*128
#define DSSM 2048
#define NHEADS 32
#define HEADDIM 64
#define DSTATE 128

typedef __attribute__((ext_vector_type(4))) float f32x4;
typedef __attribute__((ext_vector_type(8))) short s16x8;

__device__ __forceinline__ ushort f2bf(float x){
  union { float f; uint32_t u; } v; v.f = x;
  uint32_t r = (v.u + 0x7FFFu + ((v.u >> 16) & 1u)) >> 16;
  return (ushort)r;
}
__device__ __forceinline__ float bf2f(ushort h){
  union { uint32_t u; float f; } v; v.u = ((uint32_t)h) << 16;
  return v.f;
}

// ---------------- zero ----------------
__global__ void zero_kernel(float* p, int n){
  int i = blockIdx.x*blockDim.x + threadIdx.x;
  if (i < n) p[i] = 0.f;
}

// ------------- transpose W (K x N) -> bf16 hi/lo (Npad x K) -------------
__global__ __launch_bounds__(256) void transq_kernel(const float* __restrict__ W,
    ushort* __restrict__ Th, ushort* __restrict__ Tl, int K, int N)
{
  __shared__ float tile[32][33];
  int tx = threadIdx.x & 31, ty = threadIdx.x >> 5;
  int n = blockIdx.x*32 + tx;
  #pragma unroll
  for (int i=0;i<4;i++){
    int k = blockIdx.y*32 + ty + i*8;
    tile[ty+i*8][tx] = (n < N) ? W[(size_t)k*N + n] : 0.f;
  }
  __syncthreads();
  #pragma unroll
  for (int i=0;i<4;i++){
    int nn = blockIdx.x*32 + ty + i*8;
    int kk = blockIdx.y*32 + tx;
    float v = tile[tx][ty+i*8];
    ushort hi = f2bf(v);
    ushort lo = f2bf(v - bf2f(hi));
    Th[(size_t)nn*K + kk] = hi;
    Tl[(size_t)nn*K + kk] = lo;
  }
}

// ------------- GEMM: C(MxN) = A(fp32 MxK) * B^T(bf16 hi/lo, NxK), 3-term split -------------
#define LDSTR 56
__global__ __launch_bounds__(256) void gemm3_kernel(
    const float* __restrict__ A, const ushort* __restrict__ BTh, const ushort* __restrict__ BTl,
    float* __restrict__ C, int K, int lda, int ldc)
{
  __shared__ ushort Ah[128*LDSTR], Al[128*LDSTR], Bh[128*LDSTR], Bl[128*LDSTR];
  int tid = threadIdx.x;
  int wid = tid >> 6, lane = tid & 63;
  int wr = wid >> 1, wc = wid & 1;
  int bm = blockIdx.y, bn = blockIdx.x;
  f32x4 acc[4][4] = {};

  int srow = tid >> 1;
  int skh  = (tid & 1) * 16;
  const float*  Ag  = A   + (size_t)(bm*128 + srow)*lda + skh;
  const ushort* Bhg = BTh + (size_t)(bn*128 + srow)*K + skh;
  const ushort* Blg = BTl + (size_t)(bn*128 + srow)*K + skh;
  int fr = lane & 15, kq = (lane >> 4) * 8;

  for (int k0 = 0; k0 < K; k0 += 32){
    // stage A: fp32 -> bf16 hi/lo
    f32x4 a0 = *(const f32x4*)(Ag + 0);
    f32x4 a1 = *(const f32x4*)(Ag + 4);
    f32x4 a2 = *(const f32x4*)(Ag + 8);
    f32x4 a3 = *(const f32x4*)(Ag + 12);
    s16x8 h0, h1, l0, l1;
    #pragma unroll
    for (int j=0;j<4;j++){
      { float x=a0[j]; ushort hh=f2bf(x); h0[j]  =(short)hh; l0[j]  =(short)f2bf(x-bf2f(hh)); }
      { float x=a1[j]; ushort hh=f2bf(x); h0[4+j]=(short)hh; l0[4+j]=(short)f2bf(x-bf2f(hh)); }
      { float x=a2[j]; ushort hh=f2bf(x); h1[j]  =(short)hh; l1[j]  =(short)f2bf(x-bf2f(hh)); }
      { float x=a3[j]; ushort hh=f2bf(x); h1[4+j]=(short)hh; l1[4+j]=(short)f2bf(x-bf2f(hh)); }
    }
    *(s16x8*)&Ah[srow*LDSTR + skh]     = h0;
    *(s16x8*)&Ah[srow*LDSTR + skh + 8] = h1;
    *(s16x8*)&Al[srow*LDSTR + skh]     = l0;
    *(s16x8*)&Al[srow*LDSTR + skh + 8] = l1;
    // stage B (already bf16 hi/lo)
    *(s16x8*)&Bh[srow*LDSTR + skh]     = *(const s16x8*)(Bhg);
    *(s16x8*)&Bh[srow*LDSTR + skh + 8] = *(const s16x8*)(Bhg + 8);
    *(s16x8*)&Bl[srow*LDSTR + skh]     = *(const s16x8*)(Blg);
    *(s16x8*)&Bl[srow*LDSTR + skh + 8] = *(const s16x8*)(Blg + 8);
    __syncthreads();

    s16x8 afh[4], afl[4], bfh[4], bfl[4];
    #pragma unroll
    for (int i=0;i<4;i++){
      int ar = wr*64 + i*16 + fr;
      afh[i] = *(s16x8*)&Ah[ar*LDSTR + kq];
      afl[i] = *(s16x8*)&Al[ar*LDSTR + kq];
      int br = wc*64 + i*16 + fr;
      bfh[i] = *(s16x8*)&Bh[br*LDSTR + kq];
      bfl[i] = *(s16x8*)&Bl[br*LDSTR + kq];
    }
    #pragma unroll
    for (int i=0;i<4;i++){
      #pragma unroll
      for (int j=0;j<4;j++){
        acc[i][j] = __builtin_amdgcn_mfma_f32_16x16x32_bf16(afh[i], bfh[j], acc[i][j], 0,0,0);
        acc[i][j] = __builtin_amdgcn_mfma_f32_16x16x32_bf16(afh[i], bfl[j], acc[i][j], 0,0,0);
        acc[i][j] = __builtin_amdgcn_mfma_f32_16x16x32_bf16(afl[i], bfh[j], acc[i][j], 0,0,0);
      }
    }
    __syncthreads();
    Ag += 32; Bhg += 32; Blg += 32;
  }
  int rq = (lane >> 4) * 4;
  #pragma unroll
  for (int i=0;i<4;i++){
    #pragma unroll
    for (int j=0;j<4;j++){
      int row = bm*128 + wr*64 + i*16 + rq;
      int col = bn*128 + wc*64 + j*16 + fr;
      #pragma unroll
      for (int q=0;q<4;q++)
        C[(size_t)(row+q)*ldc + col] = acc[i][j][q];
    }
  }
}

// ------------- cumsum(theta) -> mean-over-heads cos/sin tables -------------
__global__ void cum_kernel(const float* __restrict__ zx, float* __restrict__ cosm, float* __restrict__ sinm){
  int bh = blockIdx.x; int b = bh >> 5; int h = bh & 31;
  int hd = threadIdx.x; // 64
  float cum = 0.f;
  for (int l=0;l<LSEQ;l++){
    int t = b*LSEQ + l;
    cum += zx[(size_t)t*DPROJP + 4416 + h*64 + hd];
    float s, c;
    sincosf(cum, &s, &c);
    atomicAdd(&cosm[t*64+hd], c*(1.f/32.f));
    atomicAdd(&sinm[t*64+hd], s*(1.f/32.f));
  }
}

// ------------- per-token: B/C rms+rope, dt/dA/lam/lamg pack -------------
__global__ __launch_bounds__(256) void ew_kernel(const float* __restrict__ zx,
    const float* __restrict__ cosm, const float* __restrict__ sinm,
    const float* __restrict__ dt_bias, const float* __restrict__ A_log,
    const float* __restrict__ B_bias, const float* __restrict__ C_bias,
    const float* __restrict__ Bnw, const float* __restrict__ Cnw,
    float* __restrict__ Bg, float* __restrict__ Cg, float4* __restrict__ scal)
{
  int t = blockIdx.x; int tid = threadIdx.x;
  __shared__ float red[256];
  __shared__ float nb[128], nc[128];
  const float* row = zx + (size_t)t*DPROJP;
  float v;
  if (tid < 128) v = row[4096 + tid] + B_bias[tid];
  else           v = row[4224 + (tid-128)] + C_bias[tid-128];
  red[tid] = v*v;
  __syncthreads();
  #pragma unroll
  for (int s=64; s>0; s>>=1){
    if ((tid & 127) < s) red[tid] += red[tid + s];
    __syncthreads();
  }
  float ms = red[(tid < 128) ? 0 : 128] * (1.f/128.f);
  float rs = rsqrtf(ms + 1e-5f);
  float w  = (tid < 128) ? Bnw[tid] : Cnw[tid-128];
  float nv = v * rs * w;
  if (tid < 128) nb[tid] = nv; else nc[tid-128] = nv;
  __syncthreads();
  if (tid < 64){
    float c = cosm[t*64+tid], s = sinm[t*64+tid];
    float a = nb[tid], bq = nb[tid+64];
    Bg[(size_t)t*128 + tid]      = a*c - bq*s;
    Bg[(size_t)t*128 + 64 + tid] = bq*c + a*s;
  } else if (tid < 128){
    int i = tid - 64;
    float c = cosm[t*64+i], s = sinm[t*64+i];
    float a = nc[i], bq = nc[i+64];
    Cg[(size_t)t*128 + i]      = a*c - bq*s;
    Cg[(size_t)t*128 + 64 + i] = bq*c + a*s;
  } else if (tid < 160){
    int hh = tid - 128;   // lanes 0..31 of wave 2
    float dtr = row[4352 + hh] + dt_bias[hh];
    float dtv = (dtr > 20.f) ? dtr : log1pf(expf(dtr));
    float dA  = expf(-dtv * expf(A_log[hh]));
    float lr  = row[4384 + hh];
    float lam = 1.f/(1.f + expf(-lr));
    float lg = lam;
    #pragma unroll
    for (int m=1;m<32;m<<=1) lg += __shfl_xor(lg, m, 64);
    lg *= (1.f/32.f);
    scal[(size_t)t*32 + hh] = make_float4(dtv, dA, lam, lg);
  }
}

// ------------- sequential SSM scan -------------
__global__ __launch_bounds__(256) void scan_kernel(const float* __restrict__ zx,
    const float* __restrict__ Bg, const float* __restrict__ Cg,
    const float4* __restrict__ scal, const float* __restrict__ Dp,
    float* __restrict__ ypart)
{
  int blk = blockIdx.x;            // 256 = b(2)*h(32)*dq(4)
  int dq = blk & 3, h = (blk >> 2) & 31, b = blk >> 7;
  int tid = threadIdx.x;
  int p = tid >> 2, ds = tid & 3;  // quad shares p
  int d0 = dq*32 + ds*8;
  float hreg[8] = {0,0,0,0,0,0,0,0};
  float bprev[8] = {0,0,0,0,0,0,0,0};
  float xprev = 0.f;
  float Dh = Dp[h];
  for (int l=0;l<LSEQ;l++){
    int t = b*LSEQ + l;
    float4 sc = scal[(size_t)t*32 + h];           // {dt, dA, lam, lamg}
    float4 b0 = *(const float4*)&Bg[(size_t)t*128 + d0];
    float4 b1 = *(const float4*)&Bg[(size_t)t*128 + d0 + 4];
    float4 c0 = *(const float4*)&Cg[(size_t)t*128 + d0];
    float4 c1 = *(const float4*)&Cg[(size_t)t*128 + d0 + 4];
    float xr = zx[(size_t)t*DPROJP + 2048 + h*64 + p];
    float xs = xr / (1.f + expf(-xr));            // silu
    float xe = xprev + sc.z*(xs - xprev);         // lam*x + (1-lam)*xprev
    float dtx = sc.x * xe;
    float bc[8] = {b0.x,b0.y,b0.z,b0.w,b1.x,b1.y,b1.z,b1.w};
    float cc[8] = {c0.x,c0.y,c0.z,c0.w,c1.x,c1.y,c1.z,c1.w};
    float y = 0.f;
    #pragma unroll
    for (int j=0;j<8;j++){
      float be = bprev[j] + sc.w*(bc[j]-bprev[j]);
      hreg[j] = sc.y*hreg[j] + dtx*be;
      y += hreg[j]*cc[j];
      bprev[j] = bc[j];
    }
    xprev = xs;
    y += __shfl_xor(y, 1, 64);
    y += __shfl_xor(y, 2, 64);
    if (ds == 0){
      if (dq == 0) y += Dh*xe;
      ypart[(size_t)(dq*TOK + t)*DSSM + h*64 + p] = y;
    }
  }
}

// ------------- final: sum d-partials, *silu(z), rms*norm_w -------------
__global__ __launch_bounds__(256) void fin_kernel(const float* __restrict__ zx,
    const float* __restrict__ ypart, const float* __restrict__ normw, float* __restrict__ yfin)
{
  int t = blockIdx.x; int tid = threadIdx.x;
  __shared__ float red[256];
  float vloc[8];
  float ss = 0.f;
  #pragma unroll
  for (int i=0;i<8;i++){
    int c = tid + i*256;
    float y = ypart[(size_t)t*DSSM + c]
            + ypart[(size_t)(TOK   + t)*DSSM + c]
            + ypart[(size_t)(2*TOK + t)*DSSM + c]
            + ypart[(size_t)(3*TOK + t)*DSSM + c];
    float z = zx[(size_t)t*DPROJP + c];
    float v = y * (z / (1.f + expf(-z)));
    vloc[i] = v; ss += v*v;
  }
  red[tid] = ss; __syncthreads();
  #pragma unroll
  for (int s=128; s>0; s>>=1){ if (tid < s) red[tid] += red[tid+s]; __syncthreads(); }
  float rs = rsqrtf(red[0]*(1.f/2048.f) + 1e-5f);
  #pragma unroll
  for (int i=0;i<8;i++){
    int c = tid + i*256;
    yfin[(size_t)t*DSSM + c] = vloc[i]*rs*normw[c];
  }
}

extern "C" void kernel_launch(void* const* d_in, const int* in_sizes, int n_in,
                              void* d_out, int out_size, void* d_ws, size_t ws_size,
                              hipStream_t stream)
{
  const float* u      = (const float*)d_in[0];
  const float* W_in   = (const float*)d_in[1];
  const float* W_out  = (const float*)d_in[2];
  const float* dt_bias= (const float*)d_in[3];
  const float* A_log  = (const float*)d_in[4];
  const float* Dp     = (const float*)d_in[5];
  const float* B_bias = (const float*)d_in[6];
  const float* C_bias = (const float*)d_in[7];
  const float* Bnw    = (const float*)d_in[8];
  const float* Cnw    = (const float*)d_in[9];
  const float* normw  = (const float*)d_in[10];
  float* out = (float*)d_out;

  char* ws = (char*)d_ws;
  size_t o = 0;
  auto alloc = [&](size_t bytes)->char*{
    char* r = ws + o; o = (o + bytes + 255) & ~(size_t)255; return r;
  };
  ushort* WTh  = (ushort*)alloc((size_t)DPROJP*DMODEL*2);
  ushort* WTl  = (ushort*)alloc((size_t)DPROJP*DMODEL*2);
  ushort* WoTh = (ushort*)alloc((size_t)DMODEL*DSSM*2);
  ushort* WoTl = (ushort*)alloc((size_t)DMODEL*DSSM*2);
  float*  zx   = (float*)alloc((size_t)TOK*DPROJP*4);
  float*  cosm = (float*)alloc((size_t)TOK*64*4);
  float*  sinm = (float*)alloc((size_t)TOK*64*4);
  float*  Bgb  = (float*)alloc((size_t)TOK*128*4);
  float*  Cgb  = (float*)alloc((size_t)TOK*128*4);
  float4* scal = (float4*)alloc((size_t)TOK*32*16);
  float*  ypart= (float*)alloc((size_t)4*TOK*DSSM*4);
  float*  yfin = (float*)alloc((size_t)TOK*DSSM*4);

  // zero cos/sin accumulators (they are atomically accumulated)
  zero_kernel<<<dim3((TOK*64 + 255)/256), dim3(256), 0, stream>>>(cosm, TOK*64);
  zero_kernel<<<dim3((TOK*64 + 255)/256), dim3(256), 0, stream>>>(sinm, TOK*64);

  // transpose + bf16-split weights
  transq_kernel<<<dim3(DPROJP/32, DMODEL/32), dim3(256), 0, stream>>>(W_in, WTh, WTl, DMODEL, DPROJ);
  transq_kernel<<<dim3(DMODEL/32, DSSM/32),   dim3(256), 0, stream>>>(W_out, WoTh, WoTl, DSSM, DMODEL);

  // in-proj: zx = u @ W_in   (M=1024, N=6528(pad), K=1024)
  gemm3_kernel<<<dim3(DPROJP/128, TOK/128), dim3(256), 0, stream>>>(u, WTh, WTl, zx, DMODEL, DMODEL, DPROJP);

  // cumsum + cos/sin head-means
  cum_kernel<<<dim3(64), dim3(64), 0, stream>>>(zx, cosm, sinm);

  // per-token elementwise
  ew_kernel<<<dim3(TOK), dim3(256), 0, stream>>>(zx, cosm, sinm, dt_bias, A_log,
                                                 B_bias, C_bias, Bnw, Cnw, Bgb, Cgb, scal);

  // sequential scan
  scan_kernel<<<dim3(256), dim3(256), 0, stream>>>(zx, Bgb, Cgb, scal, Dp, ypart);

  // gate + rms
  fin_kernel<<<dim3(TOK), dim3(256), 0, stream>>>(zx, ypart, normw, yfin);

  // out-proj: out = yfin @ W_out  (M=1024, N=1024, K=2048)
  gemm3_kernel<<<dim3(DMODEL/128, TOK/128), dim3(256), 0, stream>>>(yfin, WoTh, WoTl, out, DSSM, DSSM, DMODEL);
}

// Round 2
// 355.618 us; speedup vs baseline: 1.8914x; 1.8914x over previous
//
#include <hip/hip_runtime.h>
#include <hip/hip_bf16.h>
#include <cstdint>

#define TOK 1024      // B*L
#define LSEQ 512
#define DMODEL 1024
#define DPROJ 6464
#define DPROJP 6528   // padded to 51*128
#define DSSM 2048
#define NHEADS 32
#define HEADDIM 64
#define DSTATE 128
#define NCH 8
#define CL 64

typedef __attribute__((ext_vector_type(4))) float f32x4;
typedef __attribute__((ext_vector_type(8))) short s16x8;

__device__ __forceinline__ ushort f2bf(float x){
  union { float f; uint32_t u; } v; v.f = x;
  uint32_t r = (v.u + 0x7FFFu + ((v.u >> 16) & 1u)) >> 16;
  return (ushort)r;
}
__device__ __forceinline__ float bf2f(ushort h){
  union { uint32_t u; float f; } v; v.u = ((uint32_t)h) << 16;
  return v.f;
}

// ------------- transpose W (K x N) -> bf16 hi/lo (Npad x K) -------------
__global__ __launch_bounds__(256) void transq_kernel(const float* __restrict__ W,
    ushort* __restrict__ Th, ushort* __restrict__ Tl, int K, int N)
{
  __shared__ float tile[32][33];
  int tx = threadIdx.x & 31, ty = threadIdx.x >> 5;
  int n = blockIdx.x*32 + tx;
  #pragma unroll
  for (int i=0;i<4;i++){
    int k = blockIdx.y*32 + ty + i*8;
    tile[ty+i*8][tx] = (n < N) ? W[(size_t)k*N + n] : 0.f;
  }
  __syncthreads();
  #pragma unroll
  for (int i=0;i<4;i++){
    int nn = blockIdx.x*32 + ty + i*8;
    int kk = blockIdx.y*32 + tx;
    float v = tile[tx][ty+i*8];
    ushort hi = f2bf(v);
    ushort lo = f2bf(v - bf2f(hi));
    Th[(size_t)nn*K + kk] = hi;
    Tl[(size_t)nn*K + kk] = lo;
  }
}

// ------------- GEMM: C(MxN) = A(fp32 MxK) * B^T(bf16 hi/lo, NxK), 3-term split -------------
#define LDSTR 56
__global__ __launch_bounds__(256) void gemm3_kernel(
    const float* __restrict__ A, const ushort* __restrict__ BTh, const ushort* __restrict__ BTl,
    float* __restrict__ C, int K, int lda, int ldc)
{
  __shared__ ushort Ah[128*LDSTR], Al[128*LDSTR], Bh[128*LDSTR], Bl[128*LDSTR];
  int tid = threadIdx.x;
  int wid = tid >> 6, lane = tid & 63;
  int wr = wid >> 1, wc = wid & 1;
  int bm = blockIdx.y, bn = blockIdx.x;
  f32x4 acc[4][4] = {};

  int srow = tid >> 1;
  int skh  = (tid & 1) * 16;
  const float*  Ag  = A   + (size_t)(bm*128 + srow)*lda + skh;
  const ushort* Bhg = BTh + (size_t)(bn*128 + srow)*K + skh;
  const ushort* Blg = BTl + (size_t)(bn*128 + srow)*K + skh;
  int fr = lane & 15, kq = (lane >> 4) * 8;

  for (int k0 = 0; k0 < K; k0 += 32){
    f32x4 a0 = *(const f32x4*)(Ag + 0);
    f32x4 a1 = *(const f32x4*)(Ag + 4);
    f32x4 a2 = *(const f32x4*)(Ag + 8);
    f32x4 a3 = *(const f32x4*)(Ag + 12);
    s16x8 h0, h1, l0, l1;
    #pragma unroll
    for (int j=0;j<4;j++){
      { float x=a0[j]; ushort hh=f2bf(x); h0[j]  =(short)hh; l0[j]  =(short)f2bf(x-bf2f(hh)); }
      { float x=a1[j]; ushort hh=f2bf(x); h0[4+j]=(short)hh; l0[4+j]=(short)f2bf(x-bf2f(hh)); }
      { float x=a2[j]; ushort hh=f2bf(x); h1[j]  =(short)hh; l1[j]  =(short)f2bf(x-bf2f(hh)); }
      { float x=a3[j]; ushort hh=f2bf(x); h1[4+j]=(short)hh; l1[4+j]=(short)f2bf(x-bf2f(hh)); }
    }
    *(s16x8*)&Ah[srow*LDSTR + skh]     = h0;
    *(s16x8*)&Ah[srow*LDSTR + skh + 8] = h1;
    *(s16x8*)&Al[srow*LDSTR + skh]     = l0;
    *(s16x8*)&Al[srow*LDSTR + skh + 8] = l1;
    *(s16x8*)&Bh[srow*LDSTR + skh]     = *(const s16x8*)(Bhg);
    *(s16x8*)&Bh[srow*LDSTR + skh + 8] = *(const s16x8*)(Bhg + 8);
    *(s16x8*)&Bl[srow*LDSTR + skh]     = *(const s16x8*)(Blg);
    *(s16x8*)&Bl[srow*LDSTR + skh + 8] = *(const s16x8*)(Blg + 8);
    __syncthreads();

    s16x8 afh[4], afl[4], bfh[4], bfl[4];
    #pragma unroll
    for (int i=0;i<4;i++){
      int ar = wr*64 + i*16 + fr;
      afh[i] = *(s16x8*)&Ah[ar*LDSTR + kq];
      afl[i] = *(s16x8*)&Al[ar*LDSTR + kq];
      int br = wc*64 + i*16 + fr;
      bfh[i] = *(s16x8*)&Bh[br*LDSTR + kq];
      bfl[i] = *(s16x8*)&Bl[br*LDSTR + kq];
    }
    #pragma unroll
    for (int i=0;i<4;i++){
      #pragma unroll
      for (int j=0;j<4;j++){
        acc[i][j] = __builtin_amdgcn_mfma_f32_16x16x32_bf16(afh[i], bfh[j], acc[i][j], 0,0,0);
        acc[i][j] = __builtin_amdgcn_mfma_f32_16x16x32_bf16(afh[i], bfl[j], acc[i][j], 0,0,0);
        acc[i][j] = __builtin_amdgcn_mfma_f32_16x16x32_bf16(afl[i], bfh[j], acc[i][j], 0,0,0);
      }
    }
    __syncthreads();
    Ag += 32; Bhg += 32; Blg += 32;
  }
  int rq = (lane >> 4) * 4;
  #pragma unroll
  for (int i=0;i<4;i++){
    #pragma unroll
    for (int j=0;j<4;j++){
      int row = bm*128 + wr*64 + i*16 + rq;
      int col = bn*128 + wc*64 + j*16 + fr;
      #pragma unroll
      for (int q=0;q<4;q++)
        C[(size_t)(row+q)*ldc + col] = acc[i][j][q];
    }
  }
}

// ------------- cumsum(theta) + mean-over-heads cos/sin (block-parallel scan, no atomics) -------------
__global__ __launch_bounds__(512) void cum2_kernel(const float* __restrict__ zx,
    float* __restrict__ cosm, float* __restrict__ sinm)
{
  __shared__ float wsum[8];
  int b = blockIdx.x >> 6, hd = blockIdx.x & 63;
  int l = threadIdx.x, lane = l & 63, w = l >> 6;
  float accc = 0.f, accs = 0.f;
  const float* base = zx + (size_t)(b*LSEQ)*DPROJP + 4416 + hd;
  for (int h = 0; h < 32; h++){
    float x = base[(size_t)l*DPROJP + h*64];
    #pragma unroll
    for (int m=1; m<64; m<<=1){
      float v = __shfl_up(x, m, 64);
      if (lane >= m) x += v;
    }
    if (lane == 63) wsum[w] = x;
    __syncthreads();
    float pre = 0.f;
    for (int i=0;i<w;i++) pre += wsum[i];
    x += pre;
    float s, c;
    sincosf(x, &s, &c);
    accc += c; accs += s;
    __syncthreads();
  }
  int t = b*LSEQ + l;
  cosm[t*64+hd] = accc*(1.f/32.f);
  sinm[t*64+hd] = accs*(1.f/32.f);
}

// ------------- per-token: B/C rms+rope, dt/dA/lam/lamg pack -------------
__global__ __launch_bounds__(256) void ew_kernel(const float* __restrict__ zx,
    const float* __restrict__ cosm, const float* __restrict__ sinm,
    const float* __restrict__ dt_bias, const float* __restrict__ A_log,
    const float* __restrict__ B_bias, const float* __restrict__ C_bias,
    const float* __restrict__ Bnw, const float* __restrict__ Cnw,
    float* __restrict__ Bg, float* __restrict__ Cg, float4* __restrict__ scal)
{
  int t = blockIdx.x; int tid = threadIdx.x;
  __shared__ float red[256];
  __shared__ float nb[128], nc[128];
  const float* row = zx + (size_t)t*DPROJP;
  float v;
  if (tid < 128) v = row[4096 + tid] + B_bias[tid];
  else           v = row[4224 + (tid-128)] + C_bias[tid-128];
  red[tid] = v*v;
  __syncthreads();
  #pragma unroll
  for (int s=64; s>0; s>>=1){
    if ((tid & 127) < s) red[tid] += red[tid + s];
    __syncthreads();
  }
  float ms = red[(tid < 128) ? 0 : 128] * (1.f/128.f);
  float rs = rsqrtf(ms + 1e-5f);
  float w  = (tid < 128) ? Bnw[tid] : Cnw[tid-128];
  float nv = v * rs * w;
  if (tid < 128) nb[tid] = nv; else nc[tid-128] = nv;
  __syncthreads();
  if (tid < 64){
    float c = cosm[t*64+tid], s = sinm[t*64+tid];
    float a = nb[tid], bq = nb[tid+64];
    Bg[(size_t)t*128 + tid]      = a*c - bq*s;
    Bg[(size_t)t*128 + 64 + tid] = bq*c + a*s;
  } else if (tid < 128){
    int i = tid - 64;
    float c = cosm[t*64+i], s = sinm[t*64+i];
    float a = nc[i], bq = nc[i+64];
    Cg[(size_t)t*128 + i]      = a*c - bq*s;
    Cg[(size_t)t*128 + 64 + i] = bq*c + a*s;
  } else if (tid < 160){
    int hh = tid - 128;
    float dtr = row[4352 + hh] + dt_bias[hh];
    float dtv = (dtr > 20.f) ? dtr : log1pf(expf(dtr));
    float dA  = expf(-dtv * expf(A_log[hh]));
    float lr  = row[4384 + hh];
    float lam = 1.f/(1.f + expf(-lr));
    float lg = lam;
    #pragma unroll
    for (int m=1;m<32;m<<=1) lg += __shfl_xor(lg, m, 64);
    lg *= (1.f/32.f);
    scal[(size_t)t*32 + hh] = make_float4(dtv, dA, lam, lg);
  }
}

// ------------- chunked scan, pass 1: per-chunk local scan (h_in = 0) -------------
#define SCAN_STEP(PREV, CUR) { \
  float4 sc = *scp; scp += 32; \
  f32x4 b0 = *(const f32x4*)Bp; f32x4 b1 = *(const f32x4*)(Bp+4); Bp += 128; \
  f32x4 c0 = *(const f32x4*)Cp; f32x4 c1 = *(const f32x4*)(Cp+4); Cp += 128; \
  float xr = *xp; xp += DPROJP; \
  float xs = xr*__builtin_amdgcn_rcpf(1.f+__expf(-xr)); \
  float xe = xprev + sc.z*(xs-xprev); xprev = xs; \
  float dtx = sc.x*xe; float a1c = dtx*sc.w; float a2c = dtx - a1c; \
  CUR[0]=b0.x; CUR[1]=b0.y; CUR[2]=b0.z; CUR[3]=b0.w; \
  CUR[4]=b1.x; CUR[5]=b1.y; CUR[6]=b1.z; CUR[7]=b1.w; \
  float cc[8] = {c0.x,c0.y,c0.z,c0.w,c1.x,c1.y,c1.z,c1.w}; \
  float y = 0.f; \
  _Pragma("unroll") \
  for (int j=0;j<8;j++){ \
    hreg[j] = sc.y*hreg[j] + (a1c*CUR[j] + a2c*PREV[j]); \
    y += hreg[j]*cc[j]; \
  } \
  pref *= sc.y; \
  if (wpref) *pA = pref; \
  pA += 32; \
  y += __shfl_xor(y, 1, 64); \
  y += __shfl_xor(y, 2, 64); \
  if (ds==0){ if (dq==0) y += Dh*xe; *yp = y; } \
  yp += DSSM; \
}

__global__ __launch_bounds__(256) void scan1_kernel(const float* __restrict__ zx,
    const float* __restrict__ Bg, const float* __restrict__ Cg,
    const float4* __restrict__ scal, const float* __restrict__ Dp,
    float* __restrict__ ypart, float* __restrict__ hcarry, float* __restrict__ prefA)
{
  int blk = blockIdx.x;            // ((b*32+h)*4+dq)*8+c  -> 2048 blocks
  int c = blk & 7, dq = (blk>>3)&3, h = (blk>>5)&31, b = blk>>10;
  int tid = threadIdx.x;
  int p = tid >> 2, ds = tid & 3;
  int d0 = dq*32 + ds*8;
  int t0 = b*LSEQ + c*CL;
  float hreg[8] = {0,0,0,0,0,0,0,0};
  float bA[8], bB[8];
  float xprev = 0.f, pref = 1.f;
  if (c > 0){
    const float* bp = Bg + (size_t)(t0-1)*128 + d0;
    #pragma unroll
    for (int j=0;j<8;j++) bA[j] = bp[j];
    float xr = zx[(size_t)(t0-1)*DPROJP + 2048 + h*64 + p];
    xprev = xr*__builtin_amdgcn_rcpf(1.f+__expf(-xr));
  } else {
    #pragma unroll
    for (int j=0;j<8;j++) bA[j] = 0.f;
  }
  float Dh = Dp[h];
  const float4* scp = scal + (size_t)t0*32 + h;
  const float*  Bp  = Bg + (size_t)t0*128 + d0;
  const float*  Cp  = Cg + (size_t)t0*128 + d0;
  const float*  xp  = zx + (size_t)t0*DPROJP + 2048 + h*64 + p;
  float* yp = ypart + (size_t)(dq*TOK + t0)*DSSM + h*64 + p;
  float* pA = prefA + (size_t)t0*32 + h;
  bool wpref = (tid == 0 && dq == 0);
  #pragma unroll 1
  for (int l=0; l<CL; l+=2){
    SCAN_STEP(bA, bB)
    SCAN_STEP(bB, bA)
  }
  float* hc = hcarry + ((((size_t)(b*32+h)*8 + c)*64 + p)*128 + d0);
  #pragma unroll
  for (int j=0;j<8;j++) hc[j] = hreg[j];
}

// ------------- pass 2: propagate carries across the 8 chunks (in-place S -> Hin) -------------
__global__ __launch_bounds__(256) void scan2_kernel(float* __restrict__ hcarry,
    const float* __restrict__ prefA)
{
  int idx = blockIdx.x*256 + threadIdx.x;      // 2*32*64*128 = 524288
  int d = idx & 127, pp = (idx >> 7) & 63, h = (idx >> 13) & 31, b = idx >> 18;
  size_t base = ((size_t)(b*32+h)*512 + pp)*128 + d;
  float Hin = 0.f;
  #pragma unroll
  for (int c=0; c<NCH; c++){
    float Atot = prefA[(size_t)(b*LSEQ + c*CL + CL-1)*32 + h];
    float S = hcarry[base + (size_t)c*8192];
    hcarry[base + (size_t)c*8192] = Hin;
    Hin = Atot*Hin + S;
  }
}

// ------------- pass 3: y correction  y_t += pref(t) * (C_t . Hin(chunk)) -------------
__global__ __launch_bounds__(256) void scan3_kernel(const float* __restrict__ Cg,
    const float* __restrict__ hcarry, const float* __restrict__ prefA,
    float* __restrict__ ypart)
{
  __shared__ float Ct[CL*128];
  __shared__ float pf[CL];
  int blk = blockIdx.x;           // (b*32+h)*8+c -> 512 blocks
  int c = blk & 7, h = (blk>>3)&31, b = blk>>8;
  int tid = threadIdx.x, p = tid >> 2, ds = tid & 3;
  int t0 = b*LSEQ + c*CL;
  float hin[32];
  const float* hp = hcarry + ((((size_t)(b*32+h)*8 + c)*64 + p)*128 + ds*32);
  #pragma unroll
  for (int k=0;k<32;k+=4){
    f32x4 v = *(const f32x4*)(hp+k);
    hin[k]=v.x; hin[k+1]=v.y; hin[k+2]=v.z; hin[k+3]=v.w;
  }
  const float4* src = (const float4*)(Cg + (size_t)t0*128);
  #pragma unroll
  for (int i=0;i<8;i++) ((float4*)Ct)[tid + i*256] = src[tid + i*256];
  if (tid < CL) pf[tid] = prefA[(size_t)(t0+tid)*32 + h];
  __syncthreads();
  float* yo = ypart + (size_t)(4*TOK + t0)*DSSM + h*64 + p;
  for (int tt=0; tt<CL; tt++){
    const float* cp = &Ct[tt*128 + ds*32];
    float dot = 0.f;
    #pragma unroll
    for (int k=0;k<32;k++) dot += cp[k]*hin[k];
    dot += __shfl_xor(dot, 1, 64);
    dot += __shfl_xor(dot, 2, 64);
    if (ds == 0) yo[(size_t)tt*DSSM] = pf[tt]*dot;
  }
}

// ------------- final: sum 5 d-partials, *silu(z), rms*norm_w -------------
__global__ __launch_bounds__(256) void fin_kernel(const float* __restrict__ zx,
    const float* __restrict__ ypart, const float* __restrict__ normw, float* __restrict__ yfin)
{
  int t = blockIdx.x; int tid = threadIdx.x;
  __shared__ float red[256];
  float vloc[8];
  float ss = 0.f;
  #pragma unroll
  for (int i=0;i<8;i++){
    int cc = tid + i*256;
    float y = ypart[(size_t)t*DSSM + cc]
            + ypart[(size_t)(TOK   + t)*DSSM + cc]
            + ypart[(size_t)(2*TOK + t)*DSSM + cc]
            + ypart[(size_t)(3*TOK + t)*DSSM + cc]
            + ypart[(size_t)(4*TOK + t)*DSSM + cc];
    float z = zx[(size_t)t*DPROJP + cc];
    float v = y * (z / (1.f + expf(-z)));
    vloc[i] = v; ss += v*v;
  }
  red[tid] = ss; __syncthreads();
  #pragma unroll
  for (int s=128; s>0; s>>=1){ if (tid < s) red[tid] += red[tid+s]; __syncthreads(); }
  float rs = rsqrtf(red[0]*(1.f/2048.f) + 1e-5f);
  #pragma unroll
  for (int i=0;i<8;i++){
    int cc = tid + i*256;
    yfin[(size_t)t*DSSM + cc] = vloc[i]*rs*normw[cc];
  }
}

extern "C" void kernel_launch(void* const* d_in, const int* in_sizes, int n_in,
                              void* d_out, int out_size, void* d_ws, size_t ws_size,
                              hipStream_t stream)
{
  const float* u      = (const float*)d_in[0];
  const float* W_in   = (const float*)d_in[1];
  const float* W_out  = (const float*)d_in[2];
  const float* dt_bias= (const float*)d_in[3];
  const float* A_log  = (const float*)d_in[4];
  const float* Dp     = (const float*)d_in[5];
  const float* B_bias = (const float*)d_in[6];
  const float* C_bias = (const float*)d_in[7];
  const float* Bnw    = (const float*)d_in[8];
  const float* Cnw    = (const float*)d_in[9];
  const float* normw  = (const float*)d_in[10];
  float* out = (float*)d_out;

  char* ws = (char*)d_ws;
  size_t o = 0;
  auto alloc = [&](size_t bytes)->char*{
    char* r = ws + o; o = (o + bytes + 255) & ~(size_t)255; return r;
  };
  ushort* WTh  = (ushort*)alloc((size_t)DPROJP*DMODEL*2);
  ushort* WTl  = (ushort*)alloc((size_t)DPROJP*DMODEL*2);
  ushort* WoTh = (ushort*)alloc((size_t)DMODEL*DSSM*2);
  ushort* WoTl = (ushort*)alloc((size_t)DMODEL*DSSM*2);
  float*  zx   = (float*)alloc((size_t)TOK*DPROJP*4);
  float*  cosm = (float*)alloc((size_t)TOK*64*4);
  float*  sinm = (float*)alloc((size_t)TOK*64*4);
  float*  Bgb  = (float*)alloc((size_t)TOK*128*4);
  float*  Cgb  = (float*)alloc((size_t)TOK*128*4);
  float4* scal = (float4*)alloc((size_t)TOK*32*16);
  float*  ypart= (float*)alloc((size_t)5*TOK*DSSM*4);
  float*  yfin = (float*)alloc((size_t)TOK*DSSM*4);
  float*  hcarry=(float*)alloc((size_t)2*32*NCH*64*128*4);
  float*  prefA =(float*)alloc((size_t)TOK*32*4);

  // transpose + bf16-split weights
  transq_kernel<<<dim3(DPROJP/32, DMODEL/32), dim3(256), 0, stream>>>(W_in, WTh, WTl, DMODEL, DPROJ);
  transq_kernel<<<dim3(DMODEL/32, DSSM/32),   dim3(256), 0, stream>>>(W_out, WoTh, WoTl, DSSM, DMODEL);

  // in-proj: zx = u @ W_in   (M=1024, N=6528(pad), K=1024)
  gemm3_kernel<<<dim3(DPROJP/128, TOK/128), dim3(256), 0, stream>>>(u, WTh, WTl, zx, DMODEL, DMODEL, DPROJP);

  // cumsum + cos/sin head-means (parallel scan over L)
  cum2_kernel<<<dim3(128), dim3(512), 0, stream>>>(zx, cosm, sinm);

  // per-token elementwise
  ew_kernel<<<dim3(TOK), dim3(256), 0, stream>>>(zx, cosm, sinm, dt_bias, A_log,
                                                 B_bias, C_bias, Bnw, Cnw, Bgb, Cgb, scal);

  // chunked scan
  scan1_kernel<<<dim3(2048), dim3(256), 0, stream>>>(zx, Bgb, Cgb, scal, Dp, ypart, hcarry, prefA);
  scan2_kernel<<<dim3(2048), dim3(256), 0, stream>>>(hcarry, prefA);
  scan3_kernel<<<dim3(512),  dim3(256), 0, stream>>>(Cgb, hcarry, prefA, ypart);

  // gate + rms
  fin_kernel<<<dim3(TOK), dim3(256), 0, stream>>>(zx, ypart, normw, yfin);

  // out-proj: out = yfin @ W_out  (M=1024, N=1024, K=2048)
  gemm3_kernel<<<dim3(DMODEL/128, TOK/128), dim3(256), 0, stream>>>(yfin, WoTh, WoTl, out, DSSM, DSSM, DMODEL);
}

// Round 3
// 293.610 us; speedup vs baseline: 2.2909x; 1.2112x over previous
//
#include <hip/hip_runtime.h>
#include <hip/hip_bf16.h>
#include <cstdint>

#define TOK 1024      // B*L
#define LSEQ 512
#define DMODEL 1024
#define DPROJ 6464
#define DPROJP 6528   // padded to 51*128
#define DSSM 2048
#define NHEADS 32
#define HEADDIM 64
#define DSTATE 128
#define NCH 8
#define CL 64

typedef __attribute__((ext_vector_type(4))) float f32x4;
typedef __attribute__((ext_vector_type(8))) short s16x8;
typedef __attribute__((ext_vector_type(4))) ushort u16x4;

__device__ __forceinline__ ushort f2bf(float x){
  union { float f; uint32_t u; } v; v.f = x;
  uint32_t r = (v.u + 0x7FFFu + ((v.u >> 16) & 1u)) >> 16;
  return (ushort)r;
}
__device__ __forceinline__ float bf2f(ushort h){
  union { uint32_t u; float f; } v; v.u = ((uint32_t)h) << 16;
  return v.f;
}

__device__ __forceinline__ void gload16(const ushort* g, ushort* l){
  __builtin_amdgcn_global_load_lds(
      (const __attribute__((address_space(1))) unsigned int*)g,
      (__attribute__((address_space(3))) unsigned int*)l, 16, 0, 0);
}

// ------------- transpose W (K x N) -> bf16 hi/lo (Npad x K) -------------
__global__ __launch_bounds__(256) void transq_kernel(const float* __restrict__ W,
    ushort* __restrict__ Th, ushort* __restrict__ Tl, int K, int N)
{
  __shared__ float tile[32][33];
  int tx = threadIdx.x & 31, ty = threadIdx.x >> 5;
  int n = blockIdx.x*32 + tx;
  #pragma unroll
  for (int i=0;i<4;i++){
    int k = blockIdx.y*32 + ty + i*8;
    tile[ty+i*8][tx] = (n < N) ? W[(size_t)k*N + n] : 0.f;
  }
  __syncthreads();
  #pragma unroll
  for (int i=0;i<4;i++){
    int nn = blockIdx.x*32 + ty + i*8;
    int kk = blockIdx.y*32 + tx;
    float v = tile[tx][ty+i*8];
    ushort hi = f2bf(v);
    ushort lo = f2bf(v - bf2f(hi));
    Th[(size_t)nn*K + kk] = hi;
    Tl[(size_t)nn*K + kk] = lo;
  }
}

// ------------- split fp32 matrix -> bf16 hi/lo (same layout) -------------
__global__ __launch_bounds__(256) void splitA_kernel(const float* __restrict__ A,
    ushort* __restrict__ H, ushort* __restrict__ Lo)
{
  int i = blockIdx.x*256 + threadIdx.x;
  f32x4 v = ((const f32x4*)A)[i];
  u16x4 h, l;
  #pragma unroll
  for (int j=0;j<4;j++){
    ushort hh = f2bf(v[j]);
    h[j] = hh; l[j] = f2bf(v[j] - bf2f(hh));
  }
  *(u16x4*)&H[(size_t)i*4]  = h;
  *(u16x4*)&Lo[(size_t)i*4] = l;
}

// ------------- GEMM: C(128x128 tiles) = A(hi/lo MxK) * B^T(hi/lo NxK), 3-term -------------
// LDS tiles laid out [kg(4)][row(128)][8k] ushort; staged by global_load_lds (lane-linear),
// fragment ds_read_b128 start-banks cover all 32 banks (16B row stride) -> conflict-free.
__global__ __launch_bounds__(256) void gemmq_kernel(
    const ushort* __restrict__ Ah, const ushort* __restrict__ Al,
    const ushort* __restrict__ Bh, const ushort* __restrict__ Bl,
    float* __restrict__ C, int K, int kLen, int ldc, int nbn, int chunk)
{
  __shared__ ushort sAh[4096], sAl[4096], sBh[4096], sBl[4096];
  int bid = blockIdx.x;
  int newL = (bid & 7)*chunk + (bid >> 3);   // XCD-chunked swizzle (bijective: grid = 8*chunk)
  int bm = newL & 7;
  int pan = newL >> 3;
  int bn = pan % nbn;
  int z  = pan / nbn;
  int k0 = z * kLen;
  C += (size_t)z * 1024 * ldc;

  int tid = threadIdx.x;
  int wid = tid >> 6, lane = tid & 63;
  int wr = wid >> 1, wc = wid & 1;
  int fr = lane & 15, kg = lane >> 4;
  f32x4 acc[4][4] = {};

  int srow = tid & 127, skg = tid >> 7;
  const ushort* gA_h = Ah + (size_t)(bm*128+srow)*K + k0 + skg*8;
  const ushort* gA_l = Al + (size_t)(bm*128+srow)*K + k0 + skg*8;
  const ushort* gB_h = Bh + (size_t)(bn*128+srow)*K + k0 + skg*8;
  const ushort* gB_l = Bl + (size_t)(bn*128+srow)*K + k0 + skg*8;
  ushort* dA_h = sAh + tid*8;
  ushort* dA_l = sAl + tid*8;
  ushort* dB_h = sBh + tid*8;
  ushort* dB_l = sBl + tid*8;

  int rA = kg*1024 + (wr*64 + fr)*8;
  int rB = kg*1024 + (wc*64 + fr)*8;
  int NK = kLen >> 5;

  // prologue: stage k-step 0
  gload16(gA_h, dA_h); gload16(gA_h+16, dA_h+2048);
  gload16(gA_l, dA_l); gload16(gA_l+16, dA_l+2048);
  gload16(gB_h, dB_h); gload16(gB_h+16, dB_h+2048);
  gload16(gB_l, dB_l); gload16(gB_l+16, dB_l+2048);

  for (int ks=0; ks<NK; ks++){
    __syncthreads();                       // staged data visible (vmcnt drained)
    s16x8 afh[4], afl[4], bfh[4], bfl[4];
    #pragma unroll
    for (int i=0;i<4;i++){
      afh[i] = *(const s16x8*)&sAh[rA + i*128];
      afl[i] = *(const s16x8*)&sAl[rA + i*128];
      bfh[i] = *(const s16x8*)&sBh[rB + i*128];
      bfl[i] = *(const s16x8*)&sBl[rB + i*128];
    }
    __syncthreads();                       // all reads done; buffer free for restage
    if (ks+1 < NK){
      int off = (ks+1)*32;
      gload16(gA_h+off, dA_h); gload16(gA_h+off+16, dA_h+2048);
      gload16(gA_l+off, dA_l); gload16(gA_l+off+16, dA_l+2048);
      gload16(gB_h+off, dB_h); gload16(gB_h+off+16, dB_h+2048);
      gload16(gB_l+off, dB_l); gload16(gB_l+off+16, dB_l+2048);
    }
    #pragma unroll
    for (int i=0;i<4;i++){
      #pragma unroll
      for (int j=0;j<4;j++){
        acc[i][j] = __builtin_amdgcn_mfma_f32_16x16x32_bf16(afh[i], bfh[j], acc[i][j], 0,0,0);
        acc[i][j] = __builtin_amdgcn_mfma_f32_16x16x32_bf16(afh[i], bfl[j], acc[i][j], 0,0,0);
        acc[i][j] = __builtin_amdgcn_mfma_f32_16x16x32_bf16(afl[i], bfh[j], acc[i][j], 0,0,0);
      }
    }
  }
  int rq = kg * 4;
  #pragma unroll
  for (int i=0;i<4;i++){
    #pragma unroll
    for (int j=0;j<4;j++){
      int row = bm*128 + wr*64 + i*16 + rq;
      int col = bn*128 + wc*64 + j*16 + fr;
      #pragma unroll
      for (int q=0;q<4;q++)
        C[(size_t)(row+q)*ldc + col] = acc[i][j][q];
    }
  }
}

// ------------- reduce 4 split-K partials -------------
__global__ __launch_bounds__(256) void red4_kernel(const float* __restrict__ P, float* __restrict__ O){
  int i = blockIdx.x*256 + threadIdx.x;   // f32x4 units, total 262144
  f32x4 v = ((const f32x4*)P)[i];
  v += ((const f32x4*)P)[i + 262144];
  v += ((const f32x4*)P)[i + 2*262144];
  v += ((const f32x4*)P)[i + 3*262144];
  ((f32x4*)O)[i] = v;
}

// ------------- cumsum(theta) + mean-over-heads cos/sin (block-parallel scan) -------------
__global__ __launch_bounds__(512) void cum2_kernel(const float* __restrict__ zx,
    float* __restrict__ cosm, float* __restrict__ sinm)
{
  __shared__ float wsum[8];
  int b = blockIdx.x >> 6, hd = blockIdx.x & 63;
  int l = threadIdx.x, lane = l & 63, w = l >> 6;
  float accc = 0.f, accs = 0.f;
  const float* base = zx + (size_t)(b*LSEQ)*DPROJP + 4416 + hd;
  for (int h = 0; h < 32; h++){
    float x = base[(size_t)l*DPROJP + h*64];
    #pragma unroll
    for (int m=1; m<64; m<<=1){
      float v = __shfl_up(x, m, 64);
      if (lane >= m) x += v;
    }
    if (lane == 63) wsum[w] = x;
    __syncthreads();
    float pre = 0.f;
    for (int i=0;i<w;i++) pre += wsum[i];
    x += pre;
    float s, c;
    sincosf(x, &s, &c);
    accc += c; accs += s;
    __syncthreads();
  }
  int t = b*LSEQ + l;
  cosm[t*64+hd] = accc*(1.f/32.f);
  sinm[t*64+hd] = accs*(1.f/32.f);
}

// ------------- per-token: B/C rms+rope, dt/dA/lam/lamg pack -------------
__global__ __launch_bounds__(256) void ew_kernel(const float* __restrict__ zx,
    const float* __restrict__ cosm, const float* __restrict__ sinm,
    const float* __restrict__ dt_bias, const float* __restrict__ A_log,
    const float* __restrict__ B_bias, const float* __restrict__ C_bias,
    const float* __restrict__ Bnw, const float* __restrict__ Cnw,
    float* __restrict__ Bg, float* __restrict__ Cg, float4* __restrict__ scal)
{
  int t = blockIdx.x; int tid = threadIdx.x;
  __shared__ float red[256];
  __shared__ float nb[128], nc[128];
  const float* row = zx + (size_t)t*DPROJP;
  float v;
  if (tid < 128) v = row[4096 + tid] + B_bias[tid];
  else           v = row[4224 + (tid-128)] + C_bias[tid-128];
  red[tid] = v*v;
  __syncthreads();
  #pragma unroll
  for (int s=64; s>0; s>>=1){
    if ((tid & 127) < s) red[tid] += red[tid + s];
    __syncthreads();
  }
  float ms = red[(tid < 128) ? 0 : 128] * (1.f/128.f);
  float rs = rsqrtf(ms + 1e-5f);
  float w  = (tid < 128) ? Bnw[tid] : Cnw[tid-128];
  float nv = v * rs * w;
  if (tid < 128) nb[tid] = nv; else nc[tid-128] = nv;
  __syncthreads();
  if (tid < 64){
    float c = cosm[t*64+tid], s = sinm[t*64+tid];
    float a = nb[tid], bq = nb[tid+64];
    Bg[(size_t)t*128 + tid]      = a*c - bq*s;
    Bg[(size_t)t*128 + 64 + tid] = bq*c + a*s;
  } else if (tid < 128){
    int i = tid - 64;
    float c = cosm[t*64+i], s = sinm[t*64+i];
    float a = nc[i], bq = nc[i+64];
    Cg[(size_t)t*128 + i]      = a*c - bq*s;
    Cg[(size_t)t*128 + 64 + i] = bq*c + a*s;
  } else if (tid < 160){
    int hh = tid - 128;
    float dtr = row[4352 + hh] + dt_bias[hh];
    float dtv = (dtr > 20.f) ? dtr : log1pf(expf(dtr));
    float dA  = expf(-dtv * expf(A_log[hh]));
    float lr  = row[4384 + hh];
    float lam = 1.f/(1.f + expf(-lr));
    float lg = lam;
    #pragma unroll
    for (int m=1;m<32;m<<=1) lg += __shfl_xor(lg, m, 64);
    lg *= (1.f/32.f);
    scal[(size_t)t*32 + hh] = make_float4(dtv, dA, lam, lg);
  }
}

// ------------- chunked scan, pass 1 -------------
#define SCAN_STEP(PREV, CUR) { \
  float4 sc = *scp; scp += 32; \
  f32x4 b0 = *(const f32x4*)Bp; f32x4 b1 = *(const f32x4*)(Bp+4); Bp += 128; \
  f32x4 c0 = *(const f32x4*)Cp; f32x4 c1 = *(const f32x4*)(Cp+4); Cp += 128; \
  float xr = *xp; xp += DPROJP; \
  float xs = xr*__builtin_amdgcn_rcpf(1.f+__expf(-xr)); \
  float xe = xprev + sc.z*(xs-xprev); xprev = xs; \
  float dtx = sc.x*xe; float a1c = dtx*sc.w; float a2c = dtx - a1c; \
  CUR[0]=b0.x; CUR[1]=b0.y; CUR[2]=b0.z; CUR[3]=b0.w; \
  CUR[4]=b1.x; CUR[5]=b1.y; CUR[6]=b1.z; CUR[7]=b1.w; \
  float cc[8] = {c0.x,c0.y,c0.z,c0.w,c1.x,c1.y,c1.z,c1.w}; \
  float y = 0.f; \
  _Pragma("unroll") \
  for (int j=0;j<8;j++){ \
    hreg[j] = sc.y*hreg[j] + (a1c*CUR[j] + a2c*PREV[j]); \
    y += hreg[j]*cc[j]; \
  } \
  pref *= sc.y; \
  if (wpref) *pA = pref; \
  pA += 32; \
  y += __shfl_xor(y, 1, 64); \
  y += __shfl_xor(y, 2, 64); \
  if (ds==0){ if (dq==0) y += Dh*xe; *yp = y; } \
  yp += DSSM; \
}

__global__ __launch_bounds__(256) void scan1_kernel(const float* __restrict__ zx,
    const float* __restrict__ Bg, const float* __restrict__ Cg,
    const float4* __restrict__ scal, const float* __restrict__ Dp,
    float* __restrict__ ypart, float* __restrict__ hcarry, float* __restrict__ prefA)
{
  int blk = blockIdx.x;            // ((b*32+h)*4+dq)*8+c
  int c = blk & 7, dq = (blk>>3)&3, h = (blk>>5)&31, b = blk>>10;
  int tid = threadIdx.x;
  int p = tid >> 2, ds = tid & 3;
  int d0 = dq*32 + ds*8;
  int t0 = b*LSEQ + c*CL;
  float hreg[8] = {0,0,0,0,0,0,0,0};
  float bA[8], bB[8];
  float xprev = 0.f, pref = 1.f;
  if (c > 0){
    const float* bp = Bg + (size_t)(t0-1)*128 + d0;
    #pragma unroll
    for (int j=0;j<8;j++) bA[j] = bp[j];
    float xr = zx[(size_t)(t0-1)*DPROJP + 2048 + h*64 + p];
    xprev = xr*__builtin_amdgcn_rcpf(1.f+__expf(-xr));
  } else {
    #pragma unroll
    for (int j=0;j<8;j++) bA[j] = 0.f;
  }
  float Dh = Dp[h];
  const float4* scp = scal + (size_t)t0*32 + h;
  const float*  Bp  = Bg + (size_t)t0*128 + d0;
  const float*  Cp  = Cg + (size_t)t0*128 + d0;
  const float*  xp  = zx + (size_t)t0*DPROJP + 2048 + h*64 + p;
  float* yp = ypart + (size_t)(dq*TOK + t0)*DSSM + h*64 + p;
  float* pA = prefA + (size_t)t0*32 + h;
  bool wpref = (tid == 0 && dq == 0);
  #pragma unroll 1
  for (int l=0; l<CL; l+=2){
    SCAN_STEP(bA, bB)
    SCAN_STEP(bB, bA)
  }
  float* hc = hcarry + ((((size_t)(b*32+h)*8 + c)*64 + p)*128 + d0);
  #pragma unroll
  for (int j=0;j<8;j++) hc[j] = hreg[j];
}

// ------------- pass 2: propagate carries -------------
__global__ __launch_bounds__(256) void scan2_kernel(float* __restrict__ hcarry,
    const float* __restrict__ prefA)
{
  int idx = blockIdx.x*256 + threadIdx.x;
  int d = idx & 127, pp = (idx >> 7) & 63, h = (idx >> 13) & 31, b = idx >> 18;
  size_t base = ((size_t)(b*32+h)*512 + pp)*128 + d;
  float Hin = 0.f;
  #pragma unroll
  for (int c=0; c<NCH; c++){
    float Atot = prefA[(size_t)(b*LSEQ + c*CL + CL-1)*32 + h];
    float S = hcarry[base + (size_t)c*8192];
    hcarry[base + (size_t)c*8192] = Hin;
    Hin = Atot*Hin + S;
  }
}

// ------------- pass 3: y correction -------------
__global__ __launch_bounds__(256) void scan3_kernel(const float* __restrict__ Cg,
    const float* __restrict__ hcarry, const float* __restrict__ prefA,
    float* __restrict__ ypart)
{
  __shared__ float Ct[CL*128];
  __shared__ float pf[CL];
  int blk = blockIdx.x;
  int c = blk & 7, h = (blk>>3)&31, b = blk>>8;
  int tid = threadIdx.x, p = tid >> 2, ds = tid & 3;
  int t0 = b*LSEQ + c*CL;
  float hin[32];
  const float* hp = hcarry + ((((size_t)(b*32+h)*8 + c)*64 + p)*128 + ds*32);
  #pragma unroll
  for (int k=0;k<32;k+=4){
    f32x4 v = *(const f32x4*)(hp+k);
    hin[k]=v.x; hin[k+1]=v.y; hin[k+2]=v.z; hin[k+3]=v.w;
  }
  const float4* src = (const float4*)(Cg + (size_t)t0*128);
  #pragma unroll
  for (int i=0;i<8;i++) ((float4*)Ct)[tid + i*256] = src[tid + i*256];
  if (tid < CL) pf[tid] = prefA[(size_t)(t0+tid)*32 + h];
  __syncthreads();
  float* yo = ypart + (size_t)(4*TOK + t0)*DSSM + h*64 + p;
  for (int tt=0; tt<CL; tt++){
    const float* cp = &Ct[tt*128 + ds*32];
    float dot = 0.f;
    #pragma unroll
    for (int k=0;k<32;k++) dot += cp[k]*hin[k];
    dot += __shfl_xor(dot, 1, 64);
    dot += __shfl_xor(dot, 2, 64);
    if (ds == 0) yo[(size_t)tt*DSSM] = pf[tt]*dot;
  }
}

// ------------- final: sum 5 d-partials, *silu(z), rms*norm_w -> bf16 hi/lo -------------
__global__ __launch_bounds__(256) void fin_kernel(const float* __restrict__ zx,
    const float* __restrict__ ypart, const float* __restrict__ normw,
    ushort* __restrict__ yfh, ushort* __restrict__ yfl)
{
  int t = blockIdx.x; int tid = threadIdx.x;
  __shared__ float red[256];
  float vloc[8];
  float ss = 0.f;
  #pragma unroll
  for (int i=0;i<8;i++){
    int cc = tid + i*256;
    float y = ypart[(size_t)t*DSSM + cc]
            + ypart[(size_t)(TOK   + t)*DSSM + cc]
            + ypart[(size_t)(2*TOK + t)*DSSM + cc]
            + ypart[(size_t)(3*TOK + t)*DSSM + cc]
            + ypart[(size_t)(4*TOK + t)*DSSM + cc];
    float z = zx[(size_t)t*DPROJP + cc];
    float v = y * (z / (1.f + expf(-z)));
    vloc[i] = v; ss += v*v;
  }
  red[tid] = ss; __syncthreads();
  #pragma unroll
  for (int s=128; s>0; s>>=1){ if (tid < s) red[tid] += red[tid+s]; __syncthreads(); }
  float rs = rsqrtf(red[0]*(1.f/2048.f) + 1e-5f);
  #pragma unroll
  for (int i=0;i<8;i++){
    int cc = tid + i*256;
    float vv = vloc[i]*rs*normw[cc];
    ushort hi = f2bf(vv);
    yfh[(size_t)t*DSSM + cc] = hi;
    yfl[(size_t)t*DSSM + cc] = f2bf(vv - bf2f(hi));
  }
}

extern "C" void kernel_launch(void* const* d_in, const int* in_sizes, int n_in,
                              void* d_out, int out_size, void* d_ws, size_t ws_size,
                              hipStream_t stream)
{
  const float* u      = (const float*)d_in[0];
  const float* W_in   = (const float*)d_in[1];
  const float* W_out  = (const float*)d_in[2];
  const float* dt_bias= (const float*)d_in[3];
  const float* A_log  = (const float*)d_in[4];
  const float* Dp     = (const float*)d_in[5];
  const float* B_bias = (const float*)d_in[6];
  const float* C_bias = (const float*)d_in[7];
  const float* Bnw    = (const float*)d_in[8];
  const float* Cnw    = (const float*)d_in[9];
  const float* normw  = (const float*)d_in[10];
  float* out = (float*)d_out;

  char* ws = (char*)d_ws;
  size_t o = 0;
  auto alloc = [&](size_t bytes)->char*{
    char* r = ws + o; o = (o + bytes + 255) & ~(size_t)255; return r;
  };
  ushort* WTh  = (ushort*)alloc((size_t)DPROJP*DMODEL*2);
  ushort* WTl  = (ushort*)alloc((size_t)DPROJP*DMODEL*2);
  ushort* WoTh = (ushort*)alloc((size_t)DMODEL*DSSM*2);
  ushort* WoTl = (ushort*)alloc((size_t)DMODEL*DSSM*2);
  ushort* uh   = (ushort*)alloc((size_t)TOK*DMODEL*2);
  ushort* ul   = (ushort*)alloc((size_t)TOK*DMODEL*2);
  ushort* yfh  = (ushort*)alloc((size_t)TOK*DSSM*2);
  ushort* yfl  = (ushort*)alloc((size_t)TOK*DSSM*2);
  float*  zx   = (float*)alloc((size_t)TOK*DPROJP*4);
  float*  cosm = (float*)alloc((size_t)TOK*64*4);
  float*  sinm = (float*)alloc((size_t)TOK*64*4);
  float*  Bgb  = (float*)alloc((size_t)TOK*128*4);
  float*  Cgb  = (float*)alloc((size_t)TOK*128*4);
  float4* scal = (float4*)alloc((size_t)TOK*32*16);
  float*  ypart= (float*)alloc((size_t)5*TOK*DSSM*4);
  float*  hcarry=(float*)alloc((size_t)2*32*NCH*64*128*4);
  float*  prefA =(float*)alloc((size_t)TOK*32*4);
  float*  Cpart =(float*)alloc((size_t)4*TOK*DMODEL*4);

  // weights -> transposed bf16 hi/lo
  transq_kernel<<<dim3(DPROJP/32, DMODEL/32), dim3(256), 0, stream>>>(W_in, WTh, WTl, DMODEL, DPROJ);
  transq_kernel<<<dim3(DMODEL/32, DSSM/32),   dim3(256), 0, stream>>>(W_out, WoTh, WoTl, DSSM, DMODEL);
  // u -> bf16 hi/lo
  splitA_kernel<<<dim3(TOK*DMODEL/1024), dim3(256), 0, stream>>>(u, uh, ul);

  // in-proj: zx = u @ W_in  (M=1024, N=6528, K=1024), 408 blocks, XCD-swizzled
  gemmq_kernel<<<dim3(408), dim3(256), 0, stream>>>(uh, ul, WTh, WTl, zx, DMODEL, DMODEL, DPROJP, 51, 51);

  // cumsum + cos/sin head-means
  cum2_kernel<<<dim3(128), dim3(512), 0, stream>>>(zx, cosm, sinm);

  // per-token elementwise
  ew_kernel<<<dim3(TOK), dim3(256), 0, stream>>>(zx, cosm, sinm, dt_bias, A_log,
                                                 B_bias, C_bias, Bnw, Cnw, Bgb, Cgb, scal);

  // chunked scan
  scan1_kernel<<<dim3(2048), dim3(256), 0, stream>>>(zx, Bgb, Cgb, scal, Dp, ypart, hcarry, prefA);
  scan2_kernel<<<dim3(2048), dim3(256), 0, stream>>>(hcarry, prefA);
  scan3_kernel<<<dim3(512),  dim3(256), 0, stream>>>(Cgb, hcarry, prefA, ypart);

  // gate + rms -> bf16 hi/lo
  fin_kernel<<<dim3(TOK), dim3(256), 0, stream>>>(zx, ypart, normw, yfh, yfl);

  // out-proj: split-K=4 (M=1024, N=1024, K=2048), 256 blocks
  gemmq_kernel<<<dim3(256), dim3(256), 0, stream>>>(yfh, yfl, WoTh, WoTl, Cpart, DSSM, 512, DMODEL, 8, 32);
  red4_kernel<<<dim3(TOK*DMODEL/1024), dim3(256), 0, stream>>>(Cpart, out);
}